// Round 4
// baseline (1688.249 us; speedup 1.0000x reference)
//
#include <hip/hip_runtime.h>
#include <hip/hip_bf16.h>

#define B_     8
#define N_     1025
#define C_     3200
#define H_     25
#define D_     128
#define NQKV   (3 * C_)      // 9600
#define M_REAL (B_ * N_)     // 8200
#define M_PAD  8320          // 65 * 128

typedef __bf16 bf16x8 __attribute__((ext_vector_type(8)));
typedef short  short8 __attribute__((ext_vector_type(8)));
typedef float  f32x4  __attribute__((ext_vector_type(4)));

__device__ __forceinline__ unsigned short f2bf(float f) {
    unsigned u = __builtin_bit_cast(unsigned, f);
    u += 0x7FFFu + ((u >> 16) & 1u);          // RNE; inputs are finite
    return (unsigned short)(u >> 16);
}
__device__ __forceinline__ float bf2f(unsigned short u) {
    unsigned v = ((unsigned)u) << 16;
    return __builtin_bit_cast(float, v);
}
__device__ __forceinline__ void gload_lds16(const unsigned short* g, void* lds) {
    __builtin_amdgcn_global_load_lds(
        (const __attribute__((address_space(1))) void*)g,
        (__attribute__((address_space(3))) void*)lds, 16, 0, 0);
}

// ---------------- fp32 -> bf16 convert, with zero tail padding ----------------
__global__ __launch_bounds__(256) void convert_pad(const float* __restrict__ src,
                                                   unsigned short* __restrict__ dst,
                                                   long n_src, long n_tot) {
    long e = ((long)blockIdx.x * 256 + threadIdx.x) * 4;
    if (e >= n_tot) return;
    ushort4 o;
    if (e < n_src) {
        float4 v = *reinterpret_cast<const float4*>(src + e);
        o.x = f2bf(v.x); o.y = f2bf(v.y); o.z = f2bf(v.z); o.w = f2bf(v.w);
    } else {
        o.x = o.y = o.z = o.w = 0;
    }
    *reinterpret_cast<ushort4*>(dst + e) = o;
}

// ---------------- RMSNorm (full 3200-axis) applied in place to q / k ----------------
__global__ __launch_bounds__(256) void rmsnorm_qk(unsigned short* __restrict__ qkv,
                                                  const float* __restrict__ qw,
                                                  const float* __restrict__ kw) {
    const int row = blockIdx.x;          // 0..8199
    const int seg = blockIdx.y;          // 0=q, 1=k
    unsigned short* p = qkv + (long)row * NQKV + seg * C_;
    const float* w = seg ? kw : qw;
    const int t = threadIdx.x;
    const bool has2 = t < (400 - 256);   // 3200 elems = 400 x short8

    short8 v0 = reinterpret_cast<const short8*>(p)[t];
    short8 v1;
    if (has2) v1 = reinterpret_cast<const short8*>(p)[t + 256];

    float s = 0.f;
#pragma unroll
    for (int j = 0; j < 8; ++j) { float f = bf2f((unsigned short)v0[j]); s += f * f; }
    if (has2) {
#pragma unroll
        for (int j = 0; j < 8; ++j) { float f = bf2f((unsigned short)v1[j]); s += f * f; }
    }
#pragma unroll
    for (int m = 32; m; m >>= 1) s += __shfl_xor(s, m);
    __shared__ float red[4];
    if ((t & 63) == 0) red[t >> 6] = s;
    __syncthreads();
    float tot = red[0] + red[1] + red[2] + red[3];
    float scale = rsqrtf(tot * (1.f / C_) + 1e-6f);

#pragma unroll
    for (int j = 0; j < 8; ++j) {
        float f = bf2f((unsigned short)v0[j]) * scale * w[t * 8 + j];
        v0[j] = (short)f2bf(f);
    }
    reinterpret_cast<short8*>(p)[t] = v0;
    if (has2) {
#pragma unroll
        for (int j = 0; j < 8; ++j) {
            float f = bf2f((unsigned short)v1[j]) * scale * w[(t + 256) * 8 + j];
            v1[j] = (short)f2bf(f);
        }
        reinterpret_cast<short8*>(p)[t + 256] = v1;
    }
}

// ---------------- NT GEMM: C = A(MxK) * B(NxK)^T, 128x128 tile, BK=32 (m97 structure) ----------------
template <int BF16OUT>
__global__ __launch_bounds__(256) void gemm_bt(const unsigned short* __restrict__ A,
                                               const unsigned short* __restrict__ Bm,
                                               unsigned short* __restrict__ Cb,
                                               float* __restrict__ Cf,
                                               const float* __restrict__ bias,
                                               int M, int N, int K, int MStore) {
    const int t = threadIdx.x;
    const int w = t >> 6, l = t & 63;
    const int lq = l & 15, lh = l >> 4;
    const int m0 = blockIdx.y * 128, n0 = blockIdx.x * 128;
    const int wr = w >> 1, wc = w & 1;

    __shared__ unsigned short sA[128 * 32];
    __shared__ unsigned short sB[128 * 32];

    const f32x4 fz = {0.f, 0.f, 0.f, 0.f};
    f32x4 acc[4][4];
#pragma unroll
    for (int i = 0; i < 4; ++i)
#pragma unroll
        for (int j = 0; j < 4; ++j) acc[i][j] = fz;

    const unsigned short* Abase = A + (long)m0 * K;
    const unsigned short* Bbase = Bm + (long)n0 * K;

    for (int k0 = 0; k0 < K; k0 += 32) {
        __syncthreads();
#pragma unroll
        for (int i = 0; i < 2; ++i) {
            int c = i * 256 + t;
            int row = c >> 2, slot = c & 3;         // 4 x 16B per 64B row
            gload_lds16(Abase + (long)row * K + k0 + slot * 8, (char*)sA + c * 16);
            gload_lds16(Bbase + (long)row * K + k0 + slot * 8, (char*)sB + c * 16);
        }
        __syncthreads();

        bf16x8 av[4], bv[4];
#pragma unroll
        for (int i = 0; i < 4; ++i) {
            int row = wr * 64 + i * 16 + lq;
            av[i] = *reinterpret_cast<const bf16x8*>(sA + row * 32 + lh * 8);
        }
#pragma unroll
        for (int j = 0; j < 4; ++j) {
            int row = wc * 64 + j * 16 + lq;
            bv[j] = *reinterpret_cast<const bf16x8*>(sB + row * 32 + lh * 8);
        }
#pragma unroll
        for (int i = 0; i < 4; ++i)
#pragma unroll
            for (int j = 0; j < 4; ++j)
                acc[i][j] = __builtin_amdgcn_mfma_f32_16x16x32_bf16(av[i], bv[j], acc[i][j], 0, 0, 0);
    }

#pragma unroll
    for (int i = 0; i < 4; ++i) {
#pragma unroll
        for (int r = 0; r < 4; ++r) {
            int grow = m0 + wr * 64 + i * 16 + lh * 4 + r;   // C/D: row=(l>>4)*4+reg
            if (grow >= MStore) continue;
#pragma unroll
            for (int j = 0; j < 4; ++j) {
                int gcol = n0 + wc * 64 + j * 16 + lq;       // C/D: col=lane&15
                float v = acc[i][j][r];
                if (BF16OUT)
                    Cb[(long)grow * N + gcol] = f2bf(v);
                else
                    Cf[(long)grow * N + gcol] = v + bias[gcol];
            }
        }
    }
}

// ---------------- flash attention: 64 q-rows/block (4 waves x 16), KV tile = 32 ----------------
__global__ __launch_bounds__(256) void attn_fwd(const unsigned short* __restrict__ qkv,
                                                unsigned short* __restrict__ outb) {
    const int qt = blockIdx.x, h = blockIdx.y, b = blockIdx.z;
    const int t = threadIdx.x, w = t >> 6, l = t & 63;
    const int lq = l & 15, lh = l >> 4;

    __shared__ unsigned short sK[32 * 128];     // [key][d], 16B slots XOR-swizzled via source
    __shared__ unsigned short sV[128 * 32];     // [d][key], slot-swizzled
    __shared__ unsigned short sP[4][16 * 32];   // per-wave P tile

    const int q0 = qt * 64 + w * 16;
    int qrow = q0 + lq; if (qrow > N_ - 1) qrow = N_ - 1;   // clamp; rows >= N_ never stored
    const unsigned short* qptr = qkv + (long)(b * N_ + qrow) * NQKV + h * D_;
    bf16x8 qf[4];
#pragma unroll
    for (int ds = 0; ds < 4; ++ds)
        qf[ds] = *reinterpret_cast<const bf16x8*>(qptr + ds * 32 + lh * 8);

    const f32x4 fz = {0.f, 0.f, 0.f, 0.f};
    f32x4 o[8];
#pragma unroll
    for (int nf = 0; nf < 8; ++nf) o[nf] = fz;
    float mreg[4] = {-1e30f, -1e30f, -1e30f, -1e30f};
    float lreg[4] = {0.f, 0.f, 0.f, 0.f};
    const float scale = 0.08838834764831845f;   // 1/sqrt(128)

    unsigned short* sPw = sP[w];

    for (int kt = 0; kt < 33; ++kt) {
        const int kb0 = kt * 32;
        __syncthreads();
        // stage K: linear LDS dest, swizzle applied to global source slot
#pragma unroll
        for (int i = 0; i < 2; ++i) {
            int c = i * 256 + t;
            int krow = c >> 4, slot = c & 15;
            int key = kb0 + krow; if (key > N_ - 1) key = N_ - 1;
            int sg = slot ^ (krow & 7);
            gload_lds16(qkv + (long)(b * N_ + key) * NQKV + C_ + h * D_ + sg * 8,
                        (char*)sK + c * 16);
        }
        // stage V transposed (reg round-trip), slot-XOR swizzle on writes
        {
            int kk = t >> 3, dblk = t & 7;
            int key = kb0 + kk; if (key > N_ - 1) key = N_ - 1;
            const unsigned short* vsrc = qkv + (long)(b * N_ + key) * NQKV + 2 * C_ + h * D_ + dblk * 16;
            short8 v0 = *reinterpret_cast<const short8*>(vsrc);
            short8 v1 = *reinterpret_cast<const short8*>(vsrc + 8);
#pragma unroll
            for (int j = 0; j < 8; ++j) {
                int d0 = dblk * 16 + j, d1 = d0 + 8;
                sV[d0 * 32 + ((((kk >> 3) ^ (d0 & 3))) << 3) + (kk & 7)] = (unsigned short)v0[j];
                sV[d1 * 32 + ((((kk >> 3) ^ (d1 & 3))) << 3) + (kk & 7)] = (unsigned short)v1[j];
            }
        }
        __syncthreads();

        // S = Q K^T  (16 q-rows x 32 keys per wave)
        f32x4 s0 = fz, s1 = fz;
#pragma unroll
        for (int ds = 0; ds < 4; ++ds) {
            int sl0 = (ds * 4 + lh) ^ (lq & 7);
            bf16x8 k0 = *reinterpret_cast<const bf16x8*>(sK + lq * 128 + sl0 * 8);
            s0 = __builtin_amdgcn_mfma_f32_16x16x32_bf16(qf[ds], k0, s0, 0, 0, 0);
            int kk1 = 16 + lq;
            int sl1 = (ds * 4 + lh) ^ (kk1 & 7);
            bf16x8 k1 = *reinterpret_cast<const bf16x8*>(sK + kk1 * 128 + sl1 * 8);
            s1 = __builtin_amdgcn_mfma_f32_16x16x32_bf16(qf[ds], k1, s1, 0, 0, 0);
        }
        const bool va0 = (kb0 + lq) < N_;
        const bool va1 = (kb0 + 16 + lq) < N_;
#pragma unroll
        for (int r = 0; r < 4; ++r) {
            s0[r] = va0 ? s0[r] * scale : -1e30f;
            s1[r] = va1 ? s1[r] * scale : -1e30f;
        }
        // online softmax per q-row (rows = lh*4+r, cols across the 16-lane group)
#pragma unroll
        for (int r = 0; r < 4; ++r) {
            float mx = fmaxf(s0[r], s1[r]);
#pragma unroll
            for (int msk = 1; msk < 16; msk <<= 1) mx = fmaxf(mx, __shfl_xor(mx, msk));
            float mnew = fmaxf(mreg[r], mx);
            float corr = __expf(mreg[r] - mnew);
            float p0 = __expf(s0[r] - mnew);
            float p1 = __expf(s1[r] - mnew);
            float rs = p0 + p1;
#pragma unroll
            for (int msk = 1; msk < 16; msk <<= 1) rs += __shfl_xor(rs, msk);
            lreg[r] = lreg[r] * corr + rs;
            mreg[r] = mnew;
#pragma unroll
            for (int nf = 0; nf < 8; ++nf) o[nf][r] *= corr;
            int prow = lh * 4 + r;
            int c1 = 16 + lq;
            sPw[prow * 32 + ((((lq >> 3) ^ (prow & 3))) << 3) + (lq & 7)] = f2bf(p0);
            sPw[prow * 32 + ((((c1 >> 3) ^ (prow & 3))) << 3) + (c1 & 7)] = f2bf(p1);
        }
        // PV: o(16x128) += P(16x32) * V(32x128)
        bf16x8 pa = *reinterpret_cast<const bf16x8*>(sPw + lq * 32 + ((lh ^ (lq & 3)) << 3));
#pragma unroll
        for (int nf = 0; nf < 8; ++nf) {
            int d = nf * 16 + lq;
            bf16x8 vf = *reinterpret_cast<const bf16x8*>(sV + d * 32 + ((lh ^ (d & 3)) << 3));
            o[nf] = __builtin_amdgcn_mfma_f32_16x16x32_bf16(pa, vf, o[nf], 0, 0, 0);
        }
    }

#pragma unroll
    for (int r = 0; r < 4; ++r) {
        int qr = q0 + lh * 4 + r;
        if (qr >= N_) continue;
        float inv = 1.f / lreg[r];
        unsigned short* dst = outb + (long)(b * N_ + qr) * C_ + h * D_;
#pragma unroll
        for (int nf = 0; nf < 8; ++nf)
            dst[nf * 16 + lq] = f2bf(o[nf][r] * inv);
    }
}

extern "C" void kernel_launch(void* const* d_in, const int* in_sizes, int n_in,
                              void* d_out, int out_size, void* d_ws, size_t ws_size,
                              hipStream_t stream) {
    (void)in_sizes; (void)n_in; (void)out_size; (void)ws_size;
    const float* x   = (const float*)d_in[0];
    const float* wq  = (const float*)d_in[1];
    const float* qnw = (const float*)d_in[2];
    const float* knw = (const float*)d_in[3];
    const float* wp  = (const float*)d_in[4];
    const float* bp  = (const float*)d_in[5];
    float* out = (float*)d_out;

    // workspace layout (bf16 buffers), total ~348 MB
    unsigned short* xb    = (unsigned short*)d_ws;                 // M_PAD x C
    unsigned short* wqb   = xb   + (size_t)M_PAD * C_;             // NQKV x C
    unsigned short* wpb   = wqb  + (size_t)NQKV * C_;              // C x C
    unsigned short* qkvb  = wpb  + (size_t)C_ * C_;                // M_PAD x NQKV
    unsigned short* attnb = qkvb + (size_t)M_PAD * NQKV;           // M_PAD x C

    auto cvt = [&](const float* s, unsigned short* d, long nsrc, long ntot) {
        int blocks = (int)((ntot / 4 + 255) / 256);
        convert_pad<<<blocks, 256, 0, stream>>>(s, d, nsrc, ntot);
    };
    cvt(x,  xb,  (long)M_REAL * C_, (long)M_PAD * C_);
    cvt(wq, wqb, (long)NQKV * C_,   (long)NQKV * C_);
    cvt(wp, wpb, (long)C_ * C_,     (long)C_ * C_);
    cvt(x, attnb + (size_t)M_REAL * C_, 0, (long)(M_PAD - M_REAL) * C_);  // zero pad rows

    gemm_bt<1><<<dim3(NQKV / 128, M_PAD / 128), 256, 0, stream>>>(
        xb, wqb, qkvb, nullptr, nullptr, M_PAD, NQKV, C_, M_PAD);

    rmsnorm_qk<<<dim3(M_REAL, 2), 256, 0, stream>>>(qkvb, qnw, knw);

    attn_fwd<<<dim3(17, H_, B_), 256, 0, stream>>>(qkvb, attnb);

    gemm_bt<0><<<dim3(C_ / 128, M_PAD / 128), 256, 0, stream>>>(
        attnb, wpb, nullptr, out, bp, M_PAD, C_, C_, M_REAL);
}

// Round 5
// 1475.408 us; speedup vs baseline: 1.1443x; 1.1443x over previous
//
#include <hip/hip_runtime.h>
#include <hip/hip_bf16.h>

#define B_     8
#define N_     1025
#define C_     3200
#define H_     25
#define D_     128
#define NQKV   (3 * C_)      // 9600 (segment offsets)
#define NQKVP  9728          // padded qkv row stride (38 * 256)
#define M_REAL (B_ * N_)     // 8200
#define M_PAD  8448          // 33 * 256 (also 66 * 128)

typedef __bf16 bf16x8 __attribute__((ext_vector_type(8)));
typedef short  short8 __attribute__((ext_vector_type(8)));
typedef float  f32x4  __attribute__((ext_vector_type(4)));

__device__ __forceinline__ unsigned short f2bf(float f) {
    unsigned u = __builtin_bit_cast(unsigned, f);
    u += 0x7FFFu + ((u >> 16) & 1u);          // RNE; inputs are finite
    return (unsigned short)(u >> 16);
}
__device__ __forceinline__ float bf2f(unsigned short u) {
    unsigned v = ((unsigned)u) << 16;
    return __builtin_bit_cast(float, v);
}
__device__ __forceinline__ void gload_lds16(const unsigned short* g, void* lds) {
    __builtin_amdgcn_global_load_lds(
        (const __attribute__((address_space(1))) void*)g,
        (__attribute__((address_space(3))) void*)lds, 16, 0, 0);
}

// ---------------- fp32 -> bf16 convert, with zero tail padding ----------------
__global__ __launch_bounds__(256) void convert_pad(const float* __restrict__ src,
                                                   unsigned short* __restrict__ dst,
                                                   long n_src, long n_tot) {
    long e = ((long)blockIdx.x * 256 + threadIdx.x) * 4;
    if (e >= n_tot) return;
    ushort4 o;
    if (e < n_src) {
        float4 v = *reinterpret_cast<const float4*>(src + e);
        o.x = f2bf(v.x); o.y = f2bf(v.y); o.z = f2bf(v.z); o.w = f2bf(v.w);
    } else {
        o.x = o.y = o.z = o.w = 0;
    }
    *reinterpret_cast<ushort4*>(dst + e) = o;
}

// ---------------- RMSNorm (full 3200-axis) applied in place to q / k ----------------
__global__ __launch_bounds__(256) void rmsnorm_qk(unsigned short* __restrict__ qkv,
                                                  const float* __restrict__ qw,
                                                  const float* __restrict__ kw) {
    const int row = blockIdx.x;          // 0..8199
    const int seg = blockIdx.y;          // 0=q, 1=k
    unsigned short* p = qkv + (long)row * NQKVP + seg * C_;
    const float* w = seg ? kw : qw;
    const int t = threadIdx.x;
    const bool has2 = t < (400 - 256);   // 3200 elems = 400 x short8

    short8 v0 = reinterpret_cast<const short8*>(p)[t];
    short8 v1;
    if (has2) v1 = reinterpret_cast<const short8*>(p)[t + 256];

    float s = 0.f;
#pragma unroll
    for (int j = 0; j < 8; ++j) { float f = bf2f((unsigned short)v0[j]); s += f * f; }
    if (has2) {
#pragma unroll
        for (int j = 0; j < 8; ++j) { float f = bf2f((unsigned short)v1[j]); s += f * f; }
    }
#pragma unroll
    for (int m = 32; m; m >>= 1) s += __shfl_xor(s, m);
    __shared__ float red[4];
    if ((t & 63) == 0) red[t >> 6] = s;
    __syncthreads();
    float tot = red[0] + red[1] + red[2] + red[3];
    float scale = rsqrtf(tot * (1.f / C_) + 1e-6f);

#pragma unroll
    for (int j = 0; j < 8; ++j) {
        float f = bf2f((unsigned short)v0[j]) * scale * w[t * 8 + j];
        v0[j] = (short)f2bf(f);
    }
    reinterpret_cast<short8*>(p)[t] = v0;
    if (has2) {
#pragma unroll
        for (int j = 0; j < 8; ++j) {
            float f = bf2f((unsigned short)v1[j]) * scale * w[(t + 256) * 8 + j];
            v1[j] = (short)f2bf(f);
        }
        reinterpret_cast<short8*>(p)[t + 256] = v1;
    }
}

// ---------------- pipelined NT GEMM: C = A(MxK) * B(NxK)^T, 256x256 tile, BK=32,
// 4-deep LDS ring, counted vmcnt (never drains in main loop), T2 swizzle, T5 setprio.
// M must be MT*256, output cols = NT*256 (ldc), K % 32 == 0.
#define BKT 32
__global__ __launch_bounds__(512) void gemm_pipe(const unsigned short* __restrict__ A,
                                                 const unsigned short* __restrict__ Bm,
                                                 unsigned short* __restrict__ Cb,
                                                 int K, int MT, int GN, int nwg, int ldc) {
    __shared__ unsigned short sA[4][256 * BKT];
    __shared__ unsigned short sB[4][256 * BKT];

    // T1: bijective XCD swizzle (m204) then N-strip supertiling (GN n-tiles per strip)
    int bid = blockIdx.x;
    int qq = nwg >> 3, rr = nwg & 7;
    int xcd = bid & 7, pos = bid >> 3;
    int v = (xcd < rr ? xcd * (qq + 1) : rr * (qq + 1) + (xcd - rr) * qq) + pos;
    int per = MT * GN;
    int strip = v / per, rem = v - strip * per;
    int nt = strip * GN + rem / MT, mt = rem % MT;
    const int m0 = mt * 256, n0 = nt * 256;

    const int t = threadIdx.x, w = t >> 6, l = t & 63;
    const int lq = l & 15, lh = l >> 4;
    const int wr = w >> 2, wc = w & 3;          // 2 x 4 waves, wave tile 128x64

    const unsigned short* Ab = A + (long)m0 * K;
    const unsigned short* Bb = Bm + (long)n0 * K;
    const int nk = K / BKT;

    // staging: tile = 256 rows x 32 k = 1024 x 16B slots; 512 threads -> 2 slots each.
    // dest slot c is linear (gload_lds requirement); source slot pre-swizzled so that
    // the ds_read applies slot' = slot ^ (row&3) (involution, rule 21).
    const int c0 = t, c1 = t + 512;
    const int r0 = c0 >> 2, s0 = (c0 & 3) ^ (r0 & 3);
    const int r1 = c1 >> 2, s1 = (c1 & 3) ^ (r1 & 3);

    f32x4 acc[8][4] = {};

    auto stage = [&](int tile) {
        int k0 = tile * BKT;
        unsigned short* dA = sA[tile & 3];
        unsigned short* dB = sB[tile & 3];
        gload_lds16(Ab + (long)r0 * K + k0 + s0 * 8, (char*)dA + c0 * 16);
        gload_lds16(Ab + (long)r1 * K + k0 + s1 * 8, (char*)dA + c1 * 16);
        gload_lds16(Bb + (long)r0 * K + k0 + s0 * 8, (char*)dB + c0 * 16);
        gload_lds16(Bb + (long)r1 * K + k0 + s1 * 8, (char*)dB + c1 * 16);
    };

    stage(0); stage(1); stage(2);

    for (int tt = 0; tt < nk; ++tt) {
        // wait for tile tt's 4 loads; leave tiles tt+1, tt+2 (8 loads) in flight.
        // lgkmcnt(0) drains this wave's prior ds_reads so the post-barrier stage()
        // of tile tt+3 cannot race any wave's reads of buffer (tt-1)&3.
        if (tt + 2 < nk)      asm volatile("s_waitcnt vmcnt(8) lgkmcnt(0)" ::: "memory");
        else if (tt + 1 < nk) asm volatile("s_waitcnt vmcnt(4) lgkmcnt(0)" ::: "memory");
        else                  asm volatile("s_waitcnt vmcnt(0) lgkmcnt(0)" ::: "memory");
        __builtin_amdgcn_s_barrier();

        const unsigned short* bufA = sA[tt & 3];
        const unsigned short* bufB = sB[tt & 3];
        bf16x8 av[8], bv[4];
#pragma unroll
        for (int i = 0; i < 8; ++i) {
            int row = wr * 128 + i * 16 + lq;
            av[i] = *reinterpret_cast<const bf16x8*>(bufA + row * BKT + ((lh ^ (row & 3)) << 3));
        }
#pragma unroll
        for (int j = 0; j < 4; ++j) {
            int row = wc * 64 + j * 16 + lq;
            bv[j] = *reinterpret_cast<const bf16x8*>(bufB + row * BKT + ((lh ^ (row & 3)) << 3));
        }
        if (tt + 3 < nk) stage(tt + 3);

        __builtin_amdgcn_s_setprio(1);
#pragma unroll
        for (int i = 0; i < 8; ++i)
#pragma unroll
            for (int j = 0; j < 4; ++j)
                acc[i][j] = __builtin_amdgcn_mfma_f32_16x16x32_bf16(av[i], bv[j], acc[i][j], 0, 0, 0);
        __builtin_amdgcn_s_setprio(0);
    }

#pragma unroll
    for (int i = 0; i < 8; ++i) {
#pragma unroll
        for (int r2 = 0; r2 < 4; ++r2) {
            long grow = m0 + wr * 128 + i * 16 + lh * 4 + r2;
#pragma unroll
            for (int j = 0; j < 4; ++j) {
                int gcol = n0 + wc * 64 + j * 16 + lq;
                Cb[grow * ldc + gcol] = f2bf(acc[i][j][r2]);
            }
        }
    }
}

// ---------------- NT GEMM (m97 128x128 structure) — used for the output projection ----------------
template <int BF16OUT>
__global__ __launch_bounds__(256) void gemm_bt(const unsigned short* __restrict__ A,
                                               const unsigned short* __restrict__ Bm,
                                               unsigned short* __restrict__ Cb,
                                               float* __restrict__ Cf,
                                               const float* __restrict__ bias,
                                               int M, int N, int K, int MStore) {
    const int t = threadIdx.x;
    const int w = t >> 6, l = t & 63;
    const int lq = l & 15, lh = l >> 4;
    const int m0 = blockIdx.y * 128, n0 = blockIdx.x * 128;
    const int wr = w >> 1, wc = w & 1;

    __shared__ unsigned short sA[128 * 32];
    __shared__ unsigned short sB[128 * 32];

    const f32x4 fz = {0.f, 0.f, 0.f, 0.f};
    f32x4 acc[4][4];
#pragma unroll
    for (int i = 0; i < 4; ++i)
#pragma unroll
        for (int j = 0; j < 4; ++j) acc[i][j] = fz;

    const unsigned short* Abase = A + (long)m0 * K;
    const unsigned short* Bbase = Bm + (long)n0 * K;

    for (int k0 = 0; k0 < K; k0 += 32) {
        __syncthreads();
#pragma unroll
        for (int i = 0; i < 2; ++i) {
            int c = i * 256 + t;
            int row = c >> 2, slot = c & 3;         // 4 x 16B per 64B row
            gload_lds16(Abase + (long)row * K + k0 + slot * 8, (char*)sA + c * 16);
            gload_lds16(Bbase + (long)row * K + k0 + slot * 8, (char*)sB + c * 16);
        }
        __syncthreads();

        bf16x8 av[4], bv[4];
#pragma unroll
        for (int i = 0; i < 4; ++i) {
            int row = wr * 64 + i * 16 + lq;
            av[i] = *reinterpret_cast<const bf16x8*>(sA + row * 32 + lh * 8);
        }
#pragma unroll
        for (int j = 0; j < 4; ++j) {
            int row = wc * 64 + j * 16 + lq;
            bv[j] = *reinterpret_cast<const bf16x8*>(sB + row * 32 + lh * 8);
        }
#pragma unroll
        for (int i = 0; i < 4; ++i)
#pragma unroll
            for (int j = 0; j < 4; ++j)
                acc[i][j] = __builtin_amdgcn_mfma_f32_16x16x32_bf16(av[i], bv[j], acc[i][j], 0, 0, 0);
    }

#pragma unroll
    for (int i = 0; i < 4; ++i) {
#pragma unroll
        for (int r = 0; r < 4; ++r) {
            int grow = m0 + wr * 64 + i * 16 + lh * 4 + r;   // C/D: row=(l>>4)*4+reg
            if (grow >= MStore) continue;
#pragma unroll
            for (int j = 0; j < 4; ++j) {
                int gcol = n0 + wc * 64 + j * 16 + lq;       // C/D: col=lane&15
                float v = acc[i][j][r];
                if (BF16OUT)
                    Cb[(long)grow * N + gcol] = f2bf(v);
                else
                    Cf[(long)grow * N + gcol] = v + bias[gcol];
            }
        }
    }
}

// ---------------- flash attention: 64 q-rows/block (4 waves x 16), KV tile = 32 ----------------
__global__ __launch_bounds__(256) void attn_fwd(const unsigned short* __restrict__ qkv,
                                                unsigned short* __restrict__ outb) {
    const int qt = blockIdx.x, h = blockIdx.y, b = blockIdx.z;
    const int t = threadIdx.x, w = t >> 6, l = t & 63;
    const int lq = l & 15, lh = l >> 4;

    __shared__ unsigned short sK[32 * 128];     // [key][d], 16B slots XOR-swizzled via source
    __shared__ unsigned short sV[128 * 32];     // [d][key], slot-swizzled
    __shared__ unsigned short sP[4][16 * 32];   // per-wave P tile

    const int q0 = qt * 64 + w * 16;
    int qrow = q0 + lq; if (qrow > N_ - 1) qrow = N_ - 1;   // clamp; rows >= N_ never stored
    const unsigned short* qptr = qkv + (long)(b * N_ + qrow) * NQKVP + h * D_;
    bf16x8 qf[4];
#pragma unroll
    for (int ds = 0; ds < 4; ++ds)
        qf[ds] = *reinterpret_cast<const bf16x8*>(qptr + ds * 32 + lh * 8);

    const f32x4 fz = {0.f, 0.f, 0.f, 0.f};
    f32x4 o[8];
#pragma unroll
    for (int nf = 0; nf < 8; ++nf) o[nf] = fz;
    float mreg[4] = {-1e30f, -1e30f, -1e30f, -1e30f};
    float lreg[4] = {0.f, 0.f, 0.f, 0.f};
    const float scale = 0.08838834764831845f;   // 1/sqrt(128)

    unsigned short* sPw = sP[w];

    for (int kt = 0; kt < 33; ++kt) {
        const int kb0 = kt * 32;
        __syncthreads();
        // stage K: linear LDS dest, swizzle applied to global source slot
#pragma unroll
        for (int i = 0; i < 2; ++i) {
            int c = i * 256 + t;
            int krow = c >> 4, slot = c & 15;
            int key = kb0 + krow; if (key > N_ - 1) key = N_ - 1;
            int sg = slot ^ (krow & 7);
            gload_lds16(qkv + (long)(b * N_ + key) * NQKVP + C_ + h * D_ + sg * 8,
                        (char*)sK + c * 16);
        }
        // stage V transposed (reg round-trip), slot-XOR swizzle on writes
        {
            int kk = t >> 3, dblk = t & 7;
            int key = kb0 + kk; if (key > N_ - 1) key = N_ - 1;
            const unsigned short* vsrc = qkv + (long)(b * N_ + key) * NQKVP + 2 * C_ + h * D_ + dblk * 16;
            short8 v0 = *reinterpret_cast<const short8*>(vsrc);
            short8 v1 = *reinterpret_cast<const short8*>(vsrc + 8);
#pragma unroll
            for (int j = 0; j < 8; ++j) {
                int d0 = dblk * 16 + j, d1 = d0 + 8;
                sV[d0 * 32 + ((((kk >> 3) ^ (d0 & 3))) << 3) + (kk & 7)] = (unsigned short)v0[j];
                sV[d1 * 32 + ((((kk >> 3) ^ (d1 & 3))) << 3) + (kk & 7)] = (unsigned short)v1[j];
            }
        }
        __syncthreads();

        // S = Q K^T  (16 q-rows x 32 keys per wave)
        f32x4 s0 = fz, s1 = fz;
#pragma unroll
        for (int ds = 0; ds < 4; ++ds) {
            int sl0 = (ds * 4 + lh) ^ (lq & 7);
            bf16x8 k0 = *reinterpret_cast<const bf16x8*>(sK + lq * 128 + sl0 * 8);
            s0 = __builtin_amdgcn_mfma_f32_16x16x32_bf16(qf[ds], k0, s0, 0, 0, 0);
            int kk1 = 16 + lq;
            int sl1 = (ds * 4 + lh) ^ (kk1 & 7);
            bf16x8 k1 = *reinterpret_cast<const bf16x8*>(sK + kk1 * 128 + sl1 * 8);
            s1 = __builtin_amdgcn_mfma_f32_16x16x32_bf16(qf[ds], k1, s1, 0, 0, 0);
        }
        const bool va0 = (kb0 + lq) < N_;
        const bool va1 = (kb0 + 16 + lq) < N_;
#pragma unroll
        for (int r = 0; r < 4; ++r) {
            s0[r] = va0 ? s0[r] * scale : -1e30f;
            s1[r] = va1 ? s1[r] * scale : -1e30f;
        }
        // online softmax per q-row (rows = lh*4+r, cols across the 16-lane group)
#pragma unroll
        for (int r = 0; r < 4; ++r) {
            float mx = fmaxf(s0[r], s1[r]);
#pragma unroll
            for (int msk = 1; msk < 16; msk <<= 1) mx = fmaxf(mx, __shfl_xor(mx, msk));
            float mnew = fmaxf(mreg[r], mx);
            float corr = __expf(mreg[r] - mnew);
            float p0 = __expf(s0[r] - mnew);
            float p1 = __expf(s1[r] - mnew);
            float rs = p0 + p1;
#pragma unroll
            for (int msk = 1; msk < 16; msk <<= 1) rs += __shfl_xor(rs, msk);
            lreg[r] = lreg[r] * corr + rs;
            mreg[r] = mnew;
#pragma unroll
            for (int nf = 0; nf < 8; ++nf) o[nf][r] *= corr;
            int prow = lh * 4 + r;
            int c1 = 16 + lq;
            sPw[prow * 32 + ((((lq >> 3) ^ (prow & 3))) << 3) + (lq & 7)] = f2bf(p0);
            sPw[prow * 32 + ((((c1 >> 3) ^ (prow & 3))) << 3) + (c1 & 7)] = f2bf(p1);
        }
        // PV: o(16x128) += P(16x32) * V(32x128)
        bf16x8 pa = *reinterpret_cast<const bf16x8*>(sPw + lq * 32 + ((lh ^ (lq & 3)) << 3));
#pragma unroll
        for (int nf = 0; nf < 8; ++nf) {
            int d = nf * 16 + lq;
            bf16x8 vf = *reinterpret_cast<const bf16x8*>(sV + d * 32 + ((lh ^ (d & 3)) << 3));
            o[nf] = __builtin_amdgcn_mfma_f32_16x16x32_bf16(pa, vf, o[nf], 0, 0, 0);
        }
    }

#pragma unroll
    for (int r = 0; r < 4; ++r) {
        int qr = q0 + lh * 4 + r;
        if (qr >= N_) continue;
        float inv = 1.f / lreg[r];
        unsigned short* dst = outb + (long)(b * N_ + qr) * C_ + h * D_;
#pragma unroll
        for (int nf = 0; nf < 8; ++nf)
            dst[nf * 16 + lq] = f2bf(o[nf][r] * inv);
    }
}

extern "C" void kernel_launch(void* const* d_in, const int* in_sizes, int n_in,
                              void* d_out, int out_size, void* d_ws, size_t ws_size,
                              hipStream_t stream) {
    (void)in_sizes; (void)n_in; (void)out_size; (void)ws_size;
    const float* x   = (const float*)d_in[0];
    const float* wq  = (const float*)d_in[1];
    const float* qnw = (const float*)d_in[2];
    const float* knw = (const float*)d_in[3];
    const float* wp  = (const float*)d_in[4];
    const float* bp  = (const float*)d_in[5];
    float* out = (float*)d_out;

    // workspace layout (bf16 buffers), total ~355 MB
    unsigned short* xb    = (unsigned short*)d_ws;                 // M_PAD x C
    unsigned short* wqb   = xb   + (size_t)M_PAD * C_;             // NQKVP x C (rows >= 9600 zero)
    unsigned short* wpb   = wqb  + (size_t)NQKVP * C_;             // C x C
    unsigned short* qkvb  = wpb  + (size_t)C_ * C_;                // M_PAD x NQKVP
    unsigned short* attnb = qkvb + (size_t)M_PAD * NQKVP;          // M_PAD x C

    auto cvt = [&](const float* s, unsigned short* d, long nsrc, long ntot) {
        int blocks = (int)((ntot / 4 + 255) / 256);
        convert_pad<<<blocks, 256, 0, stream>>>(s, d, nsrc, ntot);
    };
    cvt(x,  xb,  (long)M_REAL * C_, (long)M_PAD * C_);
    cvt(wq, wqb, (long)NQKV * C_,   (long)NQKVP * C_);
    cvt(wp, wpb, (long)C_ * C_,     (long)C_ * C_);
    cvt(x, attnb + (size_t)M_REAL * C_, 0, (long)(M_PAD - M_REAL) * C_);  // zero pad rows

    // GEMM1: qkv = x * w_qkv^T  (M=8448, Ncols=9728, K=3200), pipelined 256^2 kernel
    {
        const int MT = M_PAD / 256;     // 33
        const int NT = NQKVP / 256;     // 38
        const int nwg = MT * NT;        // 1254
        gemm_pipe<<<nwg, 512, 0, stream>>>(xb, wqb, qkvb, C_, MT, 4, nwg, NQKVP);
    }

    rmsnorm_qk<<<dim3(M_REAL, 2), 256, 0, stream>>>(qkvb, qnw, knw);

    attn_fwd<<<dim3(17, H_, B_), 256, 0, stream>>>(qkvb, attnb);

    gemm_bt<0><<<dim3(C_ / 128, M_PAD / 128), 256, 0, stream>>>(
        attnb, wpb, nullptr, out, bp, M_PAD, C_, C_, M_REAL);
}

// Round 7
// 1157.577 us; speedup vs baseline: 1.4584x; 1.2746x over previous
//
#include <hip/hip_runtime.h>
#include <hip/hip_bf16.h>

#define B_     8
#define N_     1025
#define C_     3200
#define H_     25
#define D_     128
#define NQKV   (3 * C_)      // 9600 (segment offsets)
#define NQKVP  9728          // padded qkv row stride (38 * 256)
#define M_REAL (B_ * N_)     // 8200
#define M_PAD  8448          // 33 * 256
#define KVB    64
#define KPAD   1088          // 17 * 64, padded key stride of Vt

typedef __bf16 bf16x8 __attribute__((ext_vector_type(8)));
typedef short  short8 __attribute__((ext_vector_type(8)));
typedef float  f32x4  __attribute__((ext_vector_type(4)));
typedef unsigned int u32x4 __attribute__((ext_vector_type(4)));

__device__ __forceinline__ unsigned short f2bf(float f) {
    unsigned u = __builtin_bit_cast(unsigned, f);
    u += 0x7FFFu + ((u >> 16) & 1u);          // RNE; inputs are finite
    return (unsigned short)(u >> 16);
}
__device__ __forceinline__ float bf2f(unsigned short u) {
    unsigned v = ((unsigned)u) << 16;
    return __builtin_bit_cast(float, v);
}
__device__ __forceinline__ unsigned cvtpk_bf16(float lo, float hi) {
    unsigned r;
    asm("v_cvt_pk_bf16_f32 %0, %1, %2" : "=v"(r) : "v"(lo), "v"(hi));
    return r;
}
__device__ __forceinline__ void gload_lds16(const unsigned short* g, void* lds) {
    __builtin_amdgcn_global_load_lds(
        (const __attribute__((address_space(1))) void*)g,
        (__attribute__((address_space(3))) void*)lds, 16, 0, 0);
}

// ---------------- fp32 -> bf16 convert, with zero tail padding ----------------
__global__ __launch_bounds__(256) void convert_pad(const float* __restrict__ src,
                                                   unsigned short* __restrict__ dst,
                                                   long n_src, long n_tot) {
    long e = ((long)blockIdx.x * 256 + threadIdx.x) * 4;
    if (e >= n_tot) return;
    ushort4 o;
    if (e < n_src) {
        float4 v = *reinterpret_cast<const float4*>(src + e);
        o.x = f2bf(v.x); o.y = f2bf(v.y); o.z = f2bf(v.z); o.w = f2bf(v.w);
    } else {
        o.x = o.y = o.z = o.w = 0;
    }
    *reinterpret_cast<ushort4*>(dst + e) = o;
}

// ---------------- RMSNorm (full 3200-axis) in place on q / k; q also folds 1/sqrt(D) ----------------
__global__ __launch_bounds__(256) void rmsnorm_qk(unsigned short* __restrict__ qkv,
                                                  const float* __restrict__ qw,
                                                  const float* __restrict__ kw) {
    const int row = blockIdx.x;          // 0..8199
    const int seg = blockIdx.y;          // 0=q, 1=k
    unsigned short* p = qkv + (long)row * NQKVP + seg * C_;
    const float* w = seg ? kw : qw;
    const int t = threadIdx.x;
    const bool has2 = t < (400 - 256);   // 3200 elems = 400 x short8

    short8 v0 = reinterpret_cast<const short8*>(p)[t];
    short8 v1;
    if (has2) v1 = reinterpret_cast<const short8*>(p)[t + 256];

    float s = 0.f;
#pragma unroll
    for (int j = 0; j < 8; ++j) { float f = bf2f((unsigned short)v0[j]); s += f * f; }
    if (has2) {
#pragma unroll
        for (int j = 0; j < 8; ++j) { float f = bf2f((unsigned short)v1[j]); s += f * f; }
    }
#pragma unroll
    for (int m = 32; m; m >>= 1) s += __shfl_xor(s, m);
    __shared__ float red[4];
    if ((t & 63) == 0) red[t >> 6] = s;
    __syncthreads();
    float tot = red[0] + red[1] + red[2] + red[3];
    float scale = rsqrtf(tot * (1.f / C_) + 1e-6f);
    if (seg == 0) scale *= 0.08838834764831845f;   // fold attn 1/sqrt(D) into q

#pragma unroll
    for (int j = 0; j < 8; ++j) {
        float f = bf2f((unsigned short)v0[j]) * scale * w[t * 8 + j];
        v0[j] = (short)f2bf(f);
    }
    reinterpret_cast<short8*>(p)[t] = v0;
    if (has2) {
#pragma unroll
        for (int j = 0; j < 8; ++j) {
            float f = bf2f((unsigned short)v1[j]) * scale * w[(t + 256) * 8 + j];
            v1[j] = (short)f2bf(f);
        }
        reinterpret_cast<short8*>(p)[t + 256] = v1;
    }
}

// ---------------- pipelined NT GEMM: C = A(MxK) * B(NxK)^T, 256x256 tile, BK=32 ----------------
#define BKT 32
__global__ __launch_bounds__(512) void gemm_pipe(const unsigned short* __restrict__ A,
                                                 const unsigned short* __restrict__ Bm,
                                                 unsigned short* __restrict__ Cb,
                                                 int K, int MT, int GN, int nwg, int ldc) {
    __shared__ unsigned short sA[4][256 * BKT];
    __shared__ unsigned short sB[4][256 * BKT];

    int bid = blockIdx.x;
    int qq = nwg >> 3, rr = nwg & 7;
    int xcd = bid & 7, pos = bid >> 3;
    int v = (xcd < rr ? xcd * (qq + 1) : rr * (qq + 1) + (xcd - rr) * qq) + pos;
    int per = MT * GN;
    int strip = v / per, rem = v - strip * per;
    int nt = strip * GN + rem / MT, mt = rem % MT;
    const int m0 = mt * 256, n0 = nt * 256;

    const int t = threadIdx.x, w = t >> 6, l = t & 63;
    const int lq = l & 15, lh = l >> 4;
    const int wr = w >> 2, wc = w & 3;

    const unsigned short* Ab = A + (long)m0 * K;
    const unsigned short* Bb = Bm + (long)n0 * K;
    const int nk = K / BKT;

    const int c0 = t, c1 = t + 512;
    const int r0 = c0 >> 2, s0 = (c0 & 3) ^ (r0 & 3);
    const int r1 = c1 >> 2, s1 = (c1 & 3) ^ (r1 & 3);

    f32x4 acc[8][4] = {};

    auto stage = [&](int tile) {
        int k0 = tile * BKT;
        unsigned short* dA = sA[tile & 3];
        unsigned short* dB = sB[tile & 3];
        gload_lds16(Ab + (long)r0 * K + k0 + s0 * 8, (char*)dA + c0 * 16);
        gload_lds16(Ab + (long)r1 * K + k0 + s1 * 8, (char*)dA + c1 * 16);
        gload_lds16(Bb + (long)r0 * K + k0 + s0 * 8, (char*)dB + c0 * 16);
        gload_lds16(Bb + (long)r1 * K + k0 + s1 * 8, (char*)dB + c1 * 16);
    };

    stage(0); stage(1); stage(2);

    for (int tt = 0; tt < nk; ++tt) {
        if (tt + 2 < nk)      asm volatile("s_waitcnt vmcnt(8) lgkmcnt(0)" ::: "memory");
        else if (tt + 1 < nk) asm volatile("s_waitcnt vmcnt(4) lgkmcnt(0)" ::: "memory");
        else                  asm volatile("s_waitcnt vmcnt(0) lgkmcnt(0)" ::: "memory");
        __builtin_amdgcn_s_barrier();

        const unsigned short* bufA = sA[tt & 3];
        const unsigned short* bufB = sB[tt & 3];
        bf16x8 av[8], bv[4];
#pragma unroll
        for (int i = 0; i < 8; ++i) {
            int row = wr * 128 + i * 16 + lq;
            av[i] = *reinterpret_cast<const bf16x8*>(bufA + row * BKT + ((lh ^ (row & 3)) << 3));
        }
#pragma unroll
        for (int j = 0; j < 4; ++j) {
            int row = wc * 64 + j * 16 + lq;
            bv[j] = *reinterpret_cast<const bf16x8*>(bufB + row * BKT + ((lh ^ (row & 3)) << 3));
        }
        if (tt + 3 < nk) stage(tt + 3);

        __builtin_amdgcn_s_setprio(1);
#pragma unroll
        for (int i = 0; i < 8; ++i)
#pragma unroll
            for (int j = 0; j < 4; ++j)
                acc[i][j] = __builtin_amdgcn_mfma_f32_16x16x32_bf16(av[i], bv[j], acc[i][j], 0, 0, 0);
        __builtin_amdgcn_s_setprio(0);
    }

#pragma unroll
    for (int i = 0; i < 8; ++i) {
#pragma unroll
        for (int r2 = 0; r2 < 4; ++r2) {
            long grow = m0 + wr * 128 + i * 16 + lh * 4 + r2;
#pragma unroll
            for (int j = 0; j < 4; ++j) {
                int gcol = n0 + wc * 64 + j * 16 + lq;
                Cb[grow * ldc + gcol] = f2bf(acc[i][j][r2]);
            }
        }
    }
}

// ---------------- NT GEMM (m97 128x128 structure) — output projection ----------------
template <int BF16OUT>
__global__ __launch_bounds__(256) void gemm_bt(const unsigned short* __restrict__ A,
                                               const unsigned short* __restrict__ Bm,
                                               unsigned short* __restrict__ Cb,
                                               float* __restrict__ Cf,
                                               const float* __restrict__ bias,
                                               int M, int N, int K, int MStore) {
    const int t = threadIdx.x;
    const int w = t >> 6, l = t & 63;
    const int lq = l & 15, lh = l >> 4;
    const int m0 = blockIdx.y * 128, n0 = blockIdx.x * 128;
    const int wr = w >> 1, wc = w & 1;

    __shared__ unsigned short sA[128 * 32];
    __shared__ unsigned short sB[128 * 32];

    const f32x4 fz = {0.f, 0.f, 0.f, 0.f};
    f32x4 acc[4][4];
#pragma unroll
    for (int i = 0; i < 4; ++i)
#pragma unroll
        for (int j = 0; j < 4; ++j) acc[i][j] = fz;

    const unsigned short* Abase = A + (long)m0 * K;
    const unsigned short* Bbase = Bm + (long)n0 * K;

    for (int k0 = 0; k0 < K; k0 += 32) {
        __syncthreads();
#pragma unroll
        for (int i = 0; i < 2; ++i) {
            int c = i * 256 + t;
            int row = c >> 2, slot = c & 3;
            gload_lds16(Abase + (long)row * K + k0 + slot * 8, (char*)sA + c * 16);
            gload_lds16(Bbase + (long)row * K + k0 + slot * 8, (char*)sB + c * 16);
        }
        __syncthreads();

        bf16x8 av[4], bv[4];
#pragma unroll
        for (int i = 0; i < 4; ++i) {
            int row = wr * 64 + i * 16 + lq;
            av[i] = *reinterpret_cast<const bf16x8*>(sA + row * 32 + lh * 8);
        }
#pragma unroll
        for (int j = 0; j < 4; ++j) {
            int row = wc * 64 + j * 16 + lq;
            bv[j] = *reinterpret_cast<const bf16x8*>(sB + row * 32 + lh * 8);
        }
#pragma unroll
        for (int i = 0; i < 4; ++i)
#pragma unroll
            for (int j = 0; j < 4; ++j)
                acc[i][j] = __builtin_amdgcn_mfma_f32_16x16x32_bf16(av[i], bv[j], acc[i][j], 0, 0, 0);
    }

#pragma unroll
    for (int i = 0; i < 4; ++i) {
#pragma unroll
        for (int r = 0; r < 4; ++r) {
            int grow = m0 + wr * 64 + i * 16 + lh * 4 + r;
            if (grow >= MStore) continue;
#pragma unroll
            for (int j = 0; j < 4; ++j) {
                int gcol = n0 + wc * 64 + j * 16 + lq;
                float v = acc[i][j][r];
                if (BF16OUT)
                    Cb[(long)grow * N + gcol] = f2bf(v);
                else
                    Cf[(long)grow * N + gcol] = v + bias[gcol];
            }
        }
    }
}

// ---------------- V transpose: qkv v-segment [key][d] -> vtb [b][h][d][KPAD keys], zero-padded ----------------
__global__ __launch_bounds__(256) void v_transpose(const unsigned short* __restrict__ qkv,
                                                   unsigned short* __restrict__ vtb) {
    const int kt = blockIdx.x, h = blockIdx.y, b = blockIdx.z;
    const int t = threadIdx.x;
    __shared__ unsigned short tile[64][136];   // 272B row stride: 16B-aligned, bank-spread

    {
        int r = t >> 2, dq = (t & 3) * 32;
        int key = kt * 64 + r;
        int keyc = key < N_ ? key : N_ - 1;
        const unsigned short* src = qkv + ((long)(b * N_) + keyc) * NQKVP + 2 * C_ + h * D_ + dq;
        short8 a0 = *reinterpret_cast<const short8*>(src);
        short8 a1 = *reinterpret_cast<const short8*>(src + 8);
        short8 a2 = *reinterpret_cast<const short8*>(src + 16);
        short8 a3 = *reinterpret_cast<const short8*>(src + 24);
        if (key >= N_) { a0 = 0; a1 = 0; a2 = 0; a3 = 0; }
        *reinterpret_cast<short8*>(&tile[r][dq])      = a0;
        *reinterpret_cast<short8*>(&tile[r][dq + 8])  = a1;
        *reinterpret_cast<short8*>(&tile[r][dq + 16]) = a2;
        *reinterpret_cast<short8*>(&tile[r][dq + 24]) = a3;
    }
    __syncthreads();
    {
        int d = t >> 1, k0 = (t & 1) * 32;
        unsigned short* dst = vtb + ((long)(b * H_ + h) * D_ + d) * KPAD + kt * 64 + k0;
#pragma unroll
        for (int jj = 0; jj < 4; ++jj) {
            short8 g;
#pragma unroll
            for (int e = 0; e < 8; ++e) g[e] = (short)tile[k0 + jj * 8 + e][d];
            *reinterpret_cast<short8*>(dst + jj * 8) = g;
        }
    }
}

// ---------------- flash attention, swapped-QK design ----------------
// 4 waves x 32 q-rows = 128 q/block; KVB=64; S^T = mfma(K,Q) so each lane holds the
// full 64-key score row for q = lane&15 -> in-lane softmax; P exchanged in-register
// into the PV A-fragment; K and Vt staged linearly via global_load_lds with
// row-XOR source swizzle (involution applied again on ds_read, rule 21).
__global__ __launch_bounds__(256, 2) void attn_fwd(const unsigned short* __restrict__ qkv,
                                                   const unsigned short* __restrict__ vtb,
                                                   unsigned short* __restrict__ outb) {
    const int qt = blockIdx.x, h = blockIdx.y, b = blockIdx.z;
    const int t = threadIdx.x, w = t >> 6, l = t & 63;
    const int lq = l & 15, lh = l >> 4;

    __shared__ unsigned short sK[2][KVB * D_];   // [key][128d], 16 slots/row, swizzled
    __shared__ unsigned short sV[2][D_ * KVB];   // [d][64k],    8 slots/row, swizzled

    // Q fragments (q pre-scaled by 1/sqrt(D) in rmsnorm)
    const int qbase = qt * 128 + w * 32;
    bf16x8 qf[2][4];
#pragma unroll
    for (int qg = 0; qg < 2; ++qg) {
        int qrow = qbase + qg * 16 + lq; if (qrow > N_ - 1) qrow = N_ - 1;
        const unsigned short* qp = qkv + (long)(b * N_ + qrow) * NQKVP + h * D_;  // FIX: head offset
#pragma unroll
        for (int ds = 0; ds < 4; ++ds)
            qf[qg][ds] = *reinterpret_cast<const bf16x8*>(qp + ds * 32 + lh * 8);
    }

    // staging source pointers (4 slots each of K and Vt per thread)
    const unsigned short* kp[4];
    const unsigned short* vp[4];
#pragma unroll
    for (int i = 0; i < 4; ++i) {
        int slot = i * 256 + t;
        { int r = slot >> 4, sd = (slot & 15) ^ (r & 7);
          kp[i] = qkv + ((long)(b * N_) + r) * NQKVP + C_ + h * D_ + sd * 8; }
        { int d = slot >> 3, sk = (slot & 7) ^ (d & 7);
          vp[i] = vtb + ((long)(b * H_ + h) * D_ + d) * KPAD + sk * 8; }
    }
    const long kvstep = 64L * NQKVP;

    auto stageK = [&](int tile, int buf) {
        char* dst = (char*)sK[buf];
        if (tile < 16) {
            long off = (long)tile * kvstep;
#pragma unroll
            for (int i = 0; i < 4; ++i) gload_lds16(kp[i] + off, dst + (i * 256 + t) * 16);
        } else {  // tail: all rows read key 1024 (invalid k's masked in softmax)
#pragma unroll
            for (int i = 0; i < 4; ++i) {
                int slot = i * 256 + t;
                int r = slot >> 4, sd = (slot & 15) ^ (r & 7);
                const unsigned short* p = qkv + ((long)(b * N_) + (N_ - 1)) * NQKVP + C_ + h * D_ + sd * 8;
                gload_lds16(p, dst + slot * 16);
            }
        }
    };
    auto stageV = [&](int tile, int buf) {   // Vt zero-padded to KPAD: no tail clamp
        char* dst = (char*)sV[buf];
        long off = (long)tile * 64;
#pragma unroll
        for (int i = 0; i < 4; ++i) gload_lds16(vp[i] + off, dst + (i * 256 + t) * 16);
    };

    f32x4 o[2][8] = {};
    float m[2] = {-1e30f, -1e30f}, lsum[2] = {0.f, 0.f};

    stageK(0, 0); stageV(0, 0);

    for (int tt = 0; tt < 17; ++tt) {
        const int cur = tt & 1;
        if (tt < 16) { stageK(tt + 1, cur ^ 1); stageV(tt + 1, cur ^ 1); }
        if (tt < 16) asm volatile("s_waitcnt vmcnt(8)" ::: "memory");
        else         asm volatile("s_waitcnt vmcnt(0)" ::: "memory");
        __builtin_amdgcn_s_barrier();

        const unsigned short* bK = sK[cur];
        const unsigned short* bV = sV[cur];

        // S^T[k][q]: 4 chunks of 16 keys; lane holds k = c*16 + 4*lh + r, q = lq
        f32x4 s[2][4] = {};
#pragma unroll
        for (int c = 0; c < 4; ++c) {
            bf16x8 kf[4];
#pragma unroll
            for (int ds = 0; ds < 4; ++ds)
                kf[ds] = *reinterpret_cast<const bf16x8*>(
                    bK + (c * 16 + lq) * D_ + (((ds << 2) + lh) ^ (lq & 7)) * 8);
            __builtin_amdgcn_s_setprio(1);
#pragma unroll
            for (int qg = 0; qg < 2; ++qg)
#pragma unroll
                for (int ds = 0; ds < 4; ++ds)
                    s[qg][c] = __builtin_amdgcn_mfma_f32_16x16x32_bf16(kf[ds], qf[qg][ds], s[qg][c], 0, 0, 0);
            __builtin_amdgcn_s_setprio(0);
        }
        if (tt == 16) {   // mask keys >= 1025 (only k_local 0 valid)
#pragma unroll
            for (int c = 0; c < 4; ++c)
#pragma unroll
                for (int r = 0; r < 4; ++r)
                    if (c * 16 + 4 * lh + r != 0) { s[0][c][r] = -1e30f; s[1][c][r] = -1e30f; }
        }

        bf16x8 pa[2][2];
#pragma unroll
        for (int qg = 0; qg < 2; ++qg) {
            // row max over 64 keys: in-lane 16 then lanes lq+16k
            float mx = s[qg][0][0];
#pragma unroll
            for (int c = 0; c < 4; ++c)
#pragma unroll
                for (int r = 0; r < 4; ++r) mx = fmaxf(mx, s[qg][c][r]);
            mx = fmaxf(mx, __shfl_xor(mx, 16));
            mx = fmaxf(mx, __shfl_xor(mx, 32));
            if (__any(mx - m[qg] > 8.0f)) {       // T13 defer-rescale
                float mnew = fmaxf(m[qg], mx);
                float corr = __expf(m[qg] - mnew);
                lsum[qg] *= corr;
#pragma unroll
                for (int r = 0; r < 4; ++r) {
                    float co = __shfl(corr, lh * 4 + r);   // corr for o's q-row
#pragma unroll
                    for (int nf = 0; nf < 8; ++nf) o[qg][nf][r] *= co;
                }
                m[qg] = mnew;
            }
            float p[4][4]; float rs = 0.f;
#pragma unroll
            for (int c = 0; c < 4; ++c)
#pragma unroll
                for (int r = 0; r < 4; ++r) {
                    p[c][r] = __expf(s[qg][c][r] - m[qg]);
                    rs += p[c][r];
                }
            rs += __shfl_xor(rs, 16);
            rs += __shfl_xor(rs, 32);
            lsum[qg] += rs;
            // pack to bf16 and exchange into PV A-fragment: lane needs P[q=lq][k=8*lh..+8]
#pragma unroll
            for (int h2 = 0; h2 < 2; ++h2) {
                unsigned A0 = cvtpk_bf16(p[2 * h2][0], p[2 * h2][1]);
                unsigned A1 = cvtpk_bf16(p[2 * h2][2], p[2 * h2][3]);
                unsigned B0 = cvtpk_bf16(p[2 * h2 + 1][0], p[2 * h2 + 1][1]);
                unsigned B1 = cvtpk_bf16(p[2 * h2 + 1][2], p[2 * h2 + 1][3]);
                const bool lo2 = lh < 2, odd = lh & 1;
                unsigned x16_0 = __shfl_xor(lo2 ? A0 : B0, 16);
                unsigned x16_1 = __shfl_xor(lo2 ? A1 : B1, 16);
                unsigned x32_0 = __shfl_xor(lo2 ? B0 : A0, 32);
                unsigned x32_1 = __shfl_xor(lo2 ? B1 : A1, 32);
                unsigned x48_0 = __shfl_xor(odd ? B0 : A0, 48);
                unsigned x48_1 = __shfl_xor(odd ? B1 : A1, 48);
                unsigned w0 = lh == 0 ? A0 : lh == 1 ? x48_0 : lh == 2 ? x32_0 : x16_0;
                unsigned w1 = lh == 0 ? A1 : lh == 1 ? x48_1 : lh == 2 ? x32_1 : x16_1;
                unsigned w2 = lh == 0 ? x16_0 : lh == 1 ? x32_0 : lh == 2 ? x48_0 : B0;
                unsigned w3 = lh == 0 ? x16_1 : lh == 1 ? x32_1 : lh == 2 ? x48_1 : B1;
                u32x4 wv = {w0, w1, w2, w3};
                pa[qg][h2] = __builtin_bit_cast(bf16x8, wv);
            }
        }

        // PV: o[q][d] += P[q][k] * Vt[d][k]
#pragma unroll
        for (int h2 = 0; h2 < 2; ++h2) {
            bf16x8 vf[8];
#pragma unroll
            for (int nf = 0; nf < 8; ++nf)
                vf[nf] = *reinterpret_cast<const bf16x8*>(
                    bV + (nf * 16 + lq) * KVB + (((h2 << 2) + lh) ^ (lq & 7)) * 8);
            __builtin_amdgcn_s_setprio(1);
#pragma unroll
            for (int qg = 0; qg < 2; ++qg)
#pragma unroll
                for (int nf = 0; nf < 8; ++nf)
                    o[qg][nf] = __builtin_amdgcn_mfma_f32_16x16x32_bf16(pa[qg][h2], vf[nf], o[qg][nf], 0, 0, 0);
            __builtin_amdgcn_s_setprio(0);
        }
        __builtin_amdgcn_s_barrier();
    }

    // epilogue: normalize by lsum (fetched into o's row layout) and store
#pragma unroll
    for (int qg = 0; qg < 2; ++qg) {
        float linv = 1.f / lsum[qg];
#pragma unroll
        for (int r = 0; r < 4; ++r) {
            float li = __shfl(linv, lh * 4 + r);
            int row = qbase + qg * 16 + 4 * lh + r;
            if (row < N_) {
                unsigned short* dst = outb + (long)(b * N_ + row) * C_ + h * D_ + lq;
#pragma unroll
                for (int nf = 0; nf < 8; ++nf)
                    dst[nf * 16] = f2bf(o[qg][nf][r] * li);
            }
        }
    }
}

extern "C" void kernel_launch(void* const* d_in, const int* in_sizes, int n_in,
                              void* d_out, int out_size, void* d_ws, size_t ws_size,
                              hipStream_t stream) {
    (void)in_sizes; (void)n_in; (void)out_size; (void)ws_size;
    const float* x   = (const float*)d_in[0];
    const float* wq  = (const float*)d_in[1];
    const float* qnw = (const float*)d_in[2];
    const float* knw = (const float*)d_in[3];
    const float* wp  = (const float*)d_in[4];
    const float* bp  = (const float*)d_in[5];
    float* out = (float*)d_out;

    // workspace layout (bf16 buffers), ~355 MB
    unsigned short* xb    = (unsigned short*)d_ws;                 // M_PAD x C
    unsigned short* wqb   = xb   + (size_t)M_PAD * C_;             // NQKVP x C (dead after GEMM1)
    unsigned short* wpb   = wqb  + (size_t)NQKVP * C_;             // C x C
    unsigned short* qkvb  = wpb  + (size_t)C_ * C_;                // M_PAD x NQKVP
    unsigned short* attnb = qkvb + (size_t)M_PAD * NQKVP;          // M_PAD x C
    unsigned short* vtb   = wqb;   // V^T [B][H][D][KPAD] = 55.7 MB, aliases dead wqb (62.3 MB)

    auto cvt = [&](const float* s, unsigned short* d, long nsrc, long ntot) {
        int blocks = (int)((ntot / 4 + 255) / 256);
        convert_pad<<<blocks, 256, 0, stream>>>(s, d, nsrc, ntot);
    };
    cvt(x,  xb,  (long)M_REAL * C_, (long)M_PAD * C_);
    cvt(wq, wqb, (long)NQKV * C_,   (long)NQKVP * C_);
    cvt(wp, wpb, (long)C_ * C_,     (long)C_ * C_);
    cvt(x, attnb + (size_t)M_REAL * C_, 0, (long)(M_PAD - M_REAL) * C_);  // zero pad rows

    // GEMM1: qkv = x * w_qkv^T
    {
        const int MT = M_PAD / 256;     // 33
        const int NT = NQKVP / 256;     // 38
        const int nwg = MT * NT;        // 1254
        gemm_pipe<<<nwg, 512, 0, stream>>>(xb, wqb, qkvb, C_, MT, 4, nwg, NQKVP);
    }

    rmsnorm_qk<<<dim3(M_REAL, 2), 256, 0, stream>>>(qkvb, qnw, knw);

    v_transpose<<<dim3(17, H_, B_), 256, 0, stream>>>(qkvb, vtb);

    attn_fwd<<<dim3(9, H_, B_), 256, 0, stream>>>(qkvb, vtb, attnb);

    gemm_bt<0><<<dim3(C_ / 128, M_PAD / 128), 256, 0, stream>>>(
        attnb, wpb, nullptr, out, bp, M_PAD, C_, C_, M_REAL);
}

// Round 8
// 1056.406 us; speedup vs baseline: 1.5981x; 1.0958x over previous
//
#include <hip/hip_runtime.h>
#include <hip/hip_bf16.h>

#define B_     8
#define N_     1025
#define C_     3200
#define H_     25
#define D_     128
#define NQKV   (3 * C_)      // 9600 (segment offsets)
#define NQKVP  9728          // padded qkv row stride (38 * 256)
#define M_REAL (B_ * N_)     // 8200
#define M_PAD  8448          // 33 * 256
#define KVB    64
#define KPAD   1088          // 17 * 64, padded key stride of Vt
#define CPADW  3328          // 13 * 256, padded proj-weight rows

typedef __bf16 bf16x8 __attribute__((ext_vector_type(8)));
typedef short  short8 __attribute__((ext_vector_type(8)));
typedef float  f32x4  __attribute__((ext_vector_type(4)));
typedef unsigned int u32x4 __attribute__((ext_vector_type(4)));

__device__ __forceinline__ unsigned short f2bf(float f) {
    unsigned u = __builtin_bit_cast(unsigned, f);
    u += 0x7FFFu + ((u >> 16) & 1u);          // RNE; inputs are finite
    return (unsigned short)(u >> 16);
}
__device__ __forceinline__ float bf2f(unsigned short u) {
    unsigned v = ((unsigned)u) << 16;
    return __builtin_bit_cast(float, v);
}
__device__ __forceinline__ unsigned cvtpk_bf16(float lo, float hi) {
    unsigned r;
    asm("v_cvt_pk_bf16_f32 %0, %1, %2" : "=v"(r) : "v"(lo), "v"(hi));
    return r;
}
__device__ __forceinline__ void gload_lds16(const unsigned short* g, void* lds) {
    __builtin_amdgcn_global_load_lds(
        (const __attribute__((address_space(1))) void*)g,
        (__attribute__((address_space(3))) void*)lds, 16, 0, 0);
}

// ---------------- fp32 -> bf16 convert, with zero tail padding ----------------
__global__ __launch_bounds__(256) void convert_pad(const float* __restrict__ src,
                                                   unsigned short* __restrict__ dst,
                                                   long n_src, long n_tot) {
    long e = ((long)blockIdx.x * 256 + threadIdx.x) * 4;
    if (e >= n_tot) return;
    ushort4 o;
    if (e < n_src) {
        float4 v = *reinterpret_cast<const float4*>(src + e);
        o.x = f2bf(v.x); o.y = f2bf(v.y); o.z = f2bf(v.z); o.w = f2bf(v.w);
    } else {
        o.x = o.y = o.z = o.w = 0;
    }
    *reinterpret_cast<ushort4*>(dst + e) = o;
}

// ---------------- RMSNorm (full 3200-axis) in place on q / k; q also folds 1/sqrt(D) ----------------
__global__ __launch_bounds__(256) void rmsnorm_qk(unsigned short* __restrict__ qkv,
                                                  const float* __restrict__ qw,
                                                  const float* __restrict__ kw) {
    const int row = blockIdx.x;          // 0..8199
    const int seg = blockIdx.y;          // 0=q, 1=k
    unsigned short* p = qkv + (long)row * NQKVP + seg * C_;
    const float* w = seg ? kw : qw;
    const int t = threadIdx.x;
    const bool has2 = t < (400 - 256);   // 3200 elems = 400 x short8

    short8 v0 = reinterpret_cast<const short8*>(p)[t];
    short8 v1;
    if (has2) v1 = reinterpret_cast<const short8*>(p)[t + 256];

    float s = 0.f;
#pragma unroll
    for (int j = 0; j < 8; ++j) { float f = bf2f((unsigned short)v0[j]); s += f * f; }
    if (has2) {
#pragma unroll
        for (int j = 0; j < 8; ++j) { float f = bf2f((unsigned short)v1[j]); s += f * f; }
    }
#pragma unroll
    for (int m = 32; m; m >>= 1) s += __shfl_xor(s, m);
    __shared__ float red[4];
    if ((t & 63) == 0) red[t >> 6] = s;
    __syncthreads();
    float tot = red[0] + red[1] + red[2] + red[3];
    float scale = rsqrtf(tot * (1.f / C_) + 1e-6f);
    if (seg == 0) scale *= 0.08838834764831845f;   // fold attn 1/sqrt(D) into q

#pragma unroll
    for (int j = 0; j < 8; ++j) {
        float f = bf2f((unsigned short)v0[j]) * scale * w[t * 8 + j];
        v0[j] = (short)f2bf(f);
    }
    reinterpret_cast<short8*>(p)[t] = v0;
    if (has2) {
#pragma unroll
        for (int j = 0; j < 8; ++j) {
            float f = bf2f((unsigned short)v1[j]) * scale * w[(t + 256) * 8 + j];
            v1[j] = (short)f2bf(f);
        }
        reinterpret_cast<short8*>(p)[t + 256] = v1;
    }
}

// ---------------- pipelined NT GEMM: C = A(MxK) * B(NxK)^T, 256x256 tile, BK=32,
// 4-deep LDS ring, counted vmcnt, 2-way-free LDS swizzle ((row>>1)&3),
// XCD-column mapping: all XCDs sweep the same A tile; each XCD's B panel L2-resident.
#define BKT 32
template <int FP32OUT>
__global__ __launch_bounds__(512) void gemm_pipe(const unsigned short* __restrict__ A,
                                                 const unsigned short* __restrict__ Bm,
                                                 unsigned short* __restrict__ Cb,
                                                 float* __restrict__ Cf,
                                                 const float* __restrict__ bias,
                                                 int K, int MT, int NT, int ldc,
                                                 int MStore, int NStore) {
    __shared__ unsigned short sA[4][256 * BKT];
    __shared__ unsigned short sB[4][256 * BKT];

    // XCD-aligned mapping: xcd = bid&7 (dispatch round-robin), pos = step index.
    // Full strips: 8 nt-columns wide; XCD x owns column strip*8+x, m sweeps 0..MT-1.
    // All XCDs at step pos read the SAME A tile (L3 share); B panel/XCD = 1.6MB (L2-fit).
    int bid = blockIdx.x;
    int xcd = bid & 7, pos = bid >> 3;
    int nstrips = NT >> 3;                 // full strips
    int fullpos = nstrips * MT;            // per-XCD positions in full strips
    int mt, nt;
    if (pos < fullpos) {
        int strip = pos / MT;
        mt = pos - strip * MT;
        nt = strip * 8 + xcd;
    } else {
        int lin = bid - fullpos * 8;       // remainder columns, linear
        nt = nstrips * 8 + lin / MT;
        mt = lin - (lin / MT) * MT;
    }
    const int m0 = mt * 256, n0 = nt * 256;

    const int t = threadIdx.x, w = t >> 6, l = t & 63;
    const int lq = l & 15, lh = l >> 4;
    const int wr = w >> 2, wc = w & 3;

    const unsigned short* Ab = A + (long)m0 * K;
    const unsigned short* Bb = Bm + (long)n0 * K;
    const int nk = K / BKT;

    // staging: dest slot c linear (gload_lds requirement); source slot pre-swizzled
    // with s' = s ^ ((row>>1)&3) so the swizzled ds_read is an involution (rule 21).
    const int c0 = t, c1 = t + 512;
    const int r0 = c0 >> 2, s0 = (c0 & 3) ^ ((r0 >> 1) & 3);
    const int r1 = c1 >> 2, s1 = (c1 & 3) ^ ((r1 >> 1) & 3);

    f32x4 acc[8][4] = {};

    auto stage = [&](int tile) {
        int k0 = tile * BKT;
        unsigned short* dA = sA[tile & 3];
        unsigned short* dB = sB[tile & 3];
        gload_lds16(Ab + (long)r0 * K + k0 + s0 * 8, (char*)dA + c0 * 16);
        gload_lds16(Ab + (long)r1 * K + k0 + s1 * 8, (char*)dA + c1 * 16);
        gload_lds16(Bb + (long)r0 * K + k0 + s0 * 8, (char*)dB + c0 * 16);
        gload_lds16(Bb + (long)r1 * K + k0 + s1 * 8, (char*)dB + c1 * 16);
    };

    stage(0); stage(1); stage(2);

    for (int tt = 0; tt < nk; ++tt) {
        if (tt + 2 < nk)      asm volatile("s_waitcnt vmcnt(8) lgkmcnt(0)" ::: "memory");
        else if (tt + 1 < nk) asm volatile("s_waitcnt vmcnt(4) lgkmcnt(0)" ::: "memory");
        else                  asm volatile("s_waitcnt vmcnt(0) lgkmcnt(0)" ::: "memory");
        __builtin_amdgcn_s_barrier();

        const unsigned short* bufA = sA[tt & 3];
        const unsigned short* bufB = sB[tt & 3];
        bf16x8 av[8], bv[4];
#pragma unroll
        for (int i = 0; i < 8; ++i) {
            int row = wr * 128 + i * 16 + lq;
            av[i] = *reinterpret_cast<const bf16x8*>(bufA + row * BKT + ((lh ^ ((row >> 1) & 3)) << 3));
        }
#pragma unroll
        for (int j = 0; j < 4; ++j) {
            int row = wc * 64 + j * 16 + lq;
            bv[j] = *reinterpret_cast<const bf16x8*>(bufB + row * BKT + ((lh ^ ((row >> 1) & 3)) << 3));
        }
        if (tt + 3 < nk) stage(tt + 3);

        __builtin_amdgcn_s_setprio(1);
#pragma unroll
        for (int i = 0; i < 8; ++i)
#pragma unroll
            for (int j = 0; j < 4; ++j)
                acc[i][j] = __builtin_amdgcn_mfma_f32_16x16x32_bf16(av[i], bv[j], acc[i][j], 0, 0, 0);
        __builtin_amdgcn_s_setprio(0);
    }

#pragma unroll
    for (int i = 0; i < 8; ++i) {
#pragma unroll
        for (int r2 = 0; r2 < 4; ++r2) {
            long grow = m0 + wr * 128 + i * 16 + lh * 4 + r2;
            if (FP32OUT && grow >= MStore) continue;
#pragma unroll
            for (int j = 0; j < 4; ++j) {
                int gcol = n0 + wc * 64 + j * 16 + lq;
                if (FP32OUT) {
                    if (gcol < NStore)
                        Cf[grow * ldc + gcol] = acc[i][j][r2] + bias[gcol];
                } else {
                    Cb[grow * ldc + gcol] = f2bf(acc[i][j][r2]);
                }
            }
        }
    }
}

// ---------------- V transpose: qkv v-segment [key][d] -> vtb [b][h][d][KPAD keys], zero-padded ----------------
__global__ __launch_bounds__(256) void v_transpose(const unsigned short* __restrict__ qkv,
                                                   unsigned short* __restrict__ vtb) {
    const int kt = blockIdx.x, h = blockIdx.y, b = blockIdx.z;
    const int t = threadIdx.x;
    __shared__ unsigned short tile[64][136];   // 272B row stride: 16B-aligned, bank-spread

    {
        int r = t >> 2, dq = (t & 3) * 32;
        int key = kt * 64 + r;
        int keyc = key < N_ ? key : N_ - 1;
        const unsigned short* src = qkv + ((long)(b * N_) + keyc) * NQKVP + 2 * C_ + h * D_ + dq;
        short8 a0 = *reinterpret_cast<const short8*>(src);
        short8 a1 = *reinterpret_cast<const short8*>(src + 8);
        short8 a2 = *reinterpret_cast<const short8*>(src + 16);
        short8 a3 = *reinterpret_cast<const short8*>(src + 24);
        if (key >= N_) { a0 = 0; a1 = 0; a2 = 0; a3 = 0; }
        *reinterpret_cast<short8*>(&tile[r][dq])      = a0;
        *reinterpret_cast<short8*>(&tile[r][dq + 8])  = a1;
        *reinterpret_cast<short8*>(&tile[r][dq + 16]) = a2;
        *reinterpret_cast<short8*>(&tile[r][dq + 24]) = a3;
    }
    __syncthreads();
    {
        int d = t >> 1, k0 = (t & 1) * 32;
        unsigned short* dst = vtb + ((long)(b * H_ + h) * D_ + d) * KPAD + kt * 64 + k0;
#pragma unroll
        for (int jj = 0; jj < 4; ++jj) {
            short8 g;
#pragma unroll
            for (int e = 0; e < 8; ++e) g[e] = (short)tile[k0 + jj * 8 + e][d];
            *reinterpret_cast<short8*>(dst + jj * 8) = g;
        }
    }
}

// ---------------- flash attention, swapped-QK design ----------------
__global__ __launch_bounds__(256, 2) void attn_fwd(const unsigned short* __restrict__ qkv,
                                                   const unsigned short* __restrict__ vtb,
                                                   unsigned short* __restrict__ outb) {
    const int qt = blockIdx.x, h = blockIdx.y, b = blockIdx.z;
    const int t = threadIdx.x, w = t >> 6, l = t & 63;
    const int lq = l & 15, lh = l >> 4;

    __shared__ unsigned short sK[2][KVB * D_];   // [key][128d], 16 slots/row, swizzled
    __shared__ unsigned short sV[2][D_ * KVB];   // [d][64k],    8 slots/row, swizzled

    // Q fragments (q pre-scaled by 1/sqrt(D) in rmsnorm)
    const int qbase = qt * 128 + w * 32;
    bf16x8 qf[2][4];
#pragma unroll
    for (int qg = 0; qg < 2; ++qg) {
        int qrow = qbase + qg * 16 + lq; if (qrow > N_ - 1) qrow = N_ - 1;
        const unsigned short* qp = qkv + (long)(b * N_ + qrow) * NQKVP + h * D_;
#pragma unroll
        for (int ds = 0; ds < 4; ++ds)
            qf[qg][ds] = *reinterpret_cast<const bf16x8*>(qp + ds * 32 + lh * 8);
    }

    // staging source pointers (4 slots each of K and Vt per thread)
    const unsigned short* kp[4];
    const unsigned short* vp[4];
#pragma unroll
    for (int i = 0; i < 4; ++i) {
        int slot = i * 256 + t;
        { int r = slot >> 4, sd = (slot & 15) ^ (r & 7);
          kp[i] = qkv + ((long)(b * N_) + r) * NQKVP + C_ + h * D_ + sd * 8; }
        { int d = slot >> 3, sk = (slot & 7) ^ (d & 7);
          vp[i] = vtb + ((long)(b * H_ + h) * D_ + d) * KPAD + sk * 8; }
    }
    const long kvstep = 64L * NQKVP;

    auto stageK = [&](int tile, int buf) {
        char* dst = (char*)sK[buf];
        if (tile < 16) {
            long off = (long)tile * kvstep;
#pragma unroll
            for (int i = 0; i < 4; ++i) gload_lds16(kp[i] + off, dst + (i * 256 + t) * 16);
        } else {  // tail: all rows read key 1024 (invalid k's masked in softmax)
#pragma unroll
            for (int i = 0; i < 4; ++i) {
                int slot = i * 256 + t;
                int r = slot >> 4, sd = (slot & 15) ^ (r & 7);
                const unsigned short* p = qkv + ((long)(b * N_) + (N_ - 1)) * NQKVP + C_ + h * D_ + sd * 8;
                gload_lds16(p, dst + slot * 16);
            }
        }
    };
    auto stageV = [&](int tile, int buf) {   // Vt zero-padded to KPAD: no tail clamp
        char* dst = (char*)sV[buf];
        long off = (long)tile * 64;
#pragma unroll
        for (int i = 0; i < 4; ++i) gload_lds16(vp[i] + off, dst + (i * 256 + t) * 16);
    };

    f32x4 o[2][8] = {};
    float m[2] = {-1e30f, -1e30f}, lsum[2] = {0.f, 0.f};

    stageK(0, 0); stageV(0, 0);

    for (int tt = 0; tt < 17; ++tt) {
        const int cur = tt & 1;
        if (tt < 16) { stageK(tt + 1, cur ^ 1); stageV(tt + 1, cur ^ 1); }
        if (tt < 16) asm volatile("s_waitcnt vmcnt(8)" ::: "memory");
        else         asm volatile("s_waitcnt vmcnt(0)" ::: "memory");
        __builtin_amdgcn_s_barrier();

        const unsigned short* bK = sK[cur];
        const unsigned short* bV = sV[cur];

        // S^T[k][q]: 4 chunks of 16 keys; lane holds k = c*16 + 4*lh + r, q = lq
        f32x4 s[2][4] = {};
#pragma unroll
        for (int c = 0; c < 4; ++c) {
            bf16x8 kf[4];
#pragma unroll
            for (int ds = 0; ds < 4; ++ds)
                kf[ds] = *reinterpret_cast<const bf16x8*>(
                    bK + (c * 16 + lq) * D_ + (((ds << 2) + lh) ^ (lq & 7)) * 8);
            __builtin_amdgcn_s_setprio(1);
#pragma unroll
            for (int qg = 0; qg < 2; ++qg)
#pragma unroll
                for (int ds = 0; ds < 4; ++ds)
                    s[qg][c] = __builtin_amdgcn_mfma_f32_16x16x32_bf16(kf[ds], qf[qg][ds], s[qg][c], 0, 0, 0);
            __builtin_amdgcn_s_setprio(0);
        }
        if (tt == 16) {   // mask keys >= 1025 (only k_local 0 valid)
#pragma unroll
            for (int c = 0; c < 4; ++c)
#pragma unroll
                for (int r = 0; r < 4; ++r)
                    if (c * 16 + 4 * lh + r != 0) { s[0][c][r] = -1e30f; s[1][c][r] = -1e30f; }
        }

        bf16x8 pa[2][2];
#pragma unroll
        for (int qg = 0; qg < 2; ++qg) {
            // row max over 64 keys: in-lane 16 then lanes lq+16k
            float mx = s[qg][0][0];
#pragma unroll
            for (int c = 0; c < 4; ++c)
#pragma unroll
                for (int r = 0; r < 4; ++r) mx = fmaxf(mx, s[qg][c][r]);
            mx = fmaxf(mx, __shfl_xor(mx, 16));
            mx = fmaxf(mx, __shfl_xor(mx, 32));
            if (__any(mx - m[qg] > 8.0f)) {       // T13 defer-rescale
                float mnew = fmaxf(m[qg], mx);
                float corr = __expf(m[qg] - mnew);
                lsum[qg] *= corr;
#pragma unroll
                for (int r = 0; r < 4; ++r) {
                    float co = __shfl(corr, lh * 4 + r);   // corr for o's q-row
#pragma unroll
                    for (int nf = 0; nf < 8; ++nf) o[qg][nf][r] *= co;
                }
                m[qg] = mnew;
            }
            float p[4][4]; float rs = 0.f;
#pragma unroll
            for (int c = 0; c < 4; ++c)
#pragma unroll
                for (int r = 0; r < 4; ++r) {
                    p[c][r] = __expf(s[qg][c][r] - m[qg]);
                    rs += p[c][r];
                }
            rs += __shfl_xor(rs, 16);
            rs += __shfl_xor(rs, 32);
            lsum[qg] += rs;
            // pack to bf16 and exchange into PV A-fragment: lane needs P[q=lq][k=8*lh..+8]
#pragma unroll
            for (int h2 = 0; h2 < 2; ++h2) {
                unsigned A0 = cvtpk_bf16(p[2 * h2][0], p[2 * h2][1]);
                unsigned A1 = cvtpk_bf16(p[2 * h2][2], p[2 * h2][3]);
                unsigned B0 = cvtpk_bf16(p[2 * h2 + 1][0], p[2 * h2 + 1][1]);
                unsigned B1 = cvtpk_bf16(p[2 * h2 + 1][2], p[2 * h2 + 1][3]);
                const bool lo2 = lh < 2, odd = lh & 1;
                unsigned x16_0 = __shfl_xor(lo2 ? A0 : B0, 16);
                unsigned x16_1 = __shfl_xor(lo2 ? A1 : B1, 16);
                unsigned x32_0 = __shfl_xor(lo2 ? B0 : A0, 32);
                unsigned x32_1 = __shfl_xor(lo2 ? B1 : A1, 32);
                unsigned x48_0 = __shfl_xor(odd ? B0 : A0, 48);
                unsigned x48_1 = __shfl_xor(odd ? B1 : A1, 48);
                unsigned w0 = lh == 0 ? A0 : lh == 1 ? x48_0 : lh == 2 ? x32_0 : x16_0;
                unsigned w1 = lh == 0 ? A1 : lh == 1 ? x48_1 : lh == 2 ? x32_1 : x16_1;
                unsigned w2 = lh == 0 ? x16_0 : lh == 1 ? x32_0 : lh == 2 ? x48_0 : B0;
                unsigned w3 = lh == 0 ? x16_1 : lh == 1 ? x32_1 : lh == 2 ? x48_1 : B1;
                u32x4 wv = {w0, w1, w2, w3};
                pa[qg][h2] = __builtin_bit_cast(bf16x8, wv);
            }
        }

        // PV: o[q][d] += P[q][k] * Vt[d][k]
#pragma unroll
        for (int h2 = 0; h2 < 2; ++h2) {
            bf16x8 vf[8];
#pragma unroll
            for (int nf = 0; nf < 8; ++nf)
                vf[nf] = *reinterpret_cast<const bf16x8*>(
                    bV + (nf * 16 + lq) * KVB + (((h2 << 2) + lh) ^ (lq & 7)) * 8);
            __builtin_amdgcn_s_setprio(1);
#pragma unroll
            for (int qg = 0; qg < 2; ++qg)
#pragma unroll
                for (int nf = 0; nf < 8; ++nf)
                    o[qg][nf] = __builtin_amdgcn_mfma_f32_16x16x32_bf16(pa[qg][h2], vf[nf], o[qg][nf], 0, 0, 0);
            __builtin_amdgcn_s_setprio(0);
        }
        __builtin_amdgcn_s_barrier();
    }

    // epilogue: normalize by lsum (fetched into o's row layout) and store
#pragma unroll
    for (int qg = 0; qg < 2; ++qg) {
        float linv = 1.f / lsum[qg];
#pragma unroll
        for (int r = 0; r < 4; ++r) {
            float li = __shfl(linv, lh * 4 + r);
            int row = qbase + qg * 16 + 4 * lh + r;
            if (row < N_) {
                unsigned short* dst = outb + (long)(b * N_ + row) * C_ + h * D_ + lq;
#pragma unroll
                for (int nf = 0; nf < 8; ++nf)
                    dst[nf * 16] = f2bf(o[qg][nf][r] * li);
            }
        }
    }
}

extern "C" void kernel_launch(void* const* d_in, const int* in_sizes, int n_in,
                              void* d_out, int out_size, void* d_ws, size_t ws_size,
                              hipStream_t stream) {
    (void)in_sizes; (void)n_in; (void)out_size; (void)ws_size;
    const float* x   = (const float*)d_in[0];
    const float* wq  = (const float*)d_in[1];
    const float* qnw = (const float*)d_in[2];
    const float* knw = (const float*)d_in[3];
    const float* wp  = (const float*)d_in[4];
    const float* bp  = (const float*)d_in[5];
    float* out = (float*)d_out;

    // workspace layout (bf16 buffers), ~356 MB
    unsigned short* xb    = (unsigned short*)d_ws;                 // M_PAD x C
    unsigned short* wqb   = xb   + (size_t)M_PAD * C_;             // NQKVP x C (dead after GEMM1)
    unsigned short* wpb   = wqb  + (size_t)NQKVP * C_;             // CPADW x C (rows >= 3200 zero)
    unsigned short* qkvb  = wpb  + (size_t)CPADW * C_;             // M_PAD x NQKVP
    unsigned short* attnb = qkvb + (size_t)M_PAD * NQKVP;          // M_PAD x C
    unsigned short* vtb   = wqb;   // V^T [B][H][D][KPAD] = 55.7 MB, aliases dead wqb (62.3 MB)

    auto cvt = [&](const float* s, unsigned short* d, long nsrc, long ntot) {
        int blocks = (int)((ntot / 4 + 255) / 256);
        convert_pad<<<blocks, 256, 0, stream>>>(s, d, nsrc, ntot);
    };
    cvt(x,  xb,  (long)M_REAL * C_, (long)M_PAD * C_);
    cvt(wq, wqb, (long)NQKV * C_,   (long)NQKVP * C_);
    cvt(wp, wpb, (long)C_ * C_,     (long)CPADW * C_);
    cvt(x, attnb + (size_t)M_REAL * C_, 0, (long)(M_PAD - M_REAL) * C_);  // zero pad rows

    // GEMM1: qkv = x * w_qkv^T  (M=8448, Ncols=9728, K=3200)
    gemm_pipe<0><<<(M_PAD / 256) * (NQKVP / 256), 512, 0, stream>>>(
        xb, wqb, qkvb, nullptr, nullptr, C_, M_PAD / 256, NQKVP / 256, NQKVP, M_PAD, NQKVP);

    rmsnorm_qk<<<dim3(M_REAL, 2), 256, 0, stream>>>(qkvb, qnw, knw);

    v_transpose<<<dim3(17, H_, B_), 256, 0, stream>>>(qkvb, vtb);

    attn_fwd<<<dim3(9, H_, B_), 256, 0, stream>>>(qkvb, vtb, attnb);

    // GEMM2: out = attn * w_proj^T + b  (M=8448->8200, Ncols=3328->3200, K=3200)
    gemm_pipe<1><<<(M_PAD / 256) * (CPADW / 256), 512, 0, stream>>>(
        attnb, wpb, nullptr, out, bp, C_, M_PAD / 256, CPADW / 256, C_, M_REAL, C_);
}